// Round 1
// baseline (6941.201 us; speedup 1.0000x reference)
//
#include <hip/hip_runtime.h>

// ---------------------------------------------------------------------------
// GIN 3-layer forward: per layer
//   agg[i] = sum_{e:(s->i)} h[s]
//   out    = ((1+eps)*h + agg) @ W + b   (+ReLU on layers 0,1)
// ---------------------------------------------------------------------------

__global__ __launch_bounds__(256) void scatter_add_kernel(
    const float* __restrict__ X, const int* __restrict__ src,
    const int* __restrict__ dst, float* __restrict__ agg,
    int c4shift, int c4mask, long long total)
{
    long long idx = (long long)blockIdx.x * 256 + threadIdx.x;
    if (idx >= total) return;
    int e  = (int)(idx >> c4shift);
    int c4 = (int)(idx & c4mask);
    int s = src[e];
    int d = dst[e];
    const float4 v = reinterpret_cast<const float4*>(X)[((size_t)s << c4shift) + c4];
    float* dp = agg + ((((size_t)d << c4shift) + c4) << 2);
    atomicAdd(dp + 0, v.x);
    atomicAdd(dp + 1, v.y);
    atomicAdd(dp + 2, v.z);
    atomicAdd(dp + 3, v.w);
}

// 64x64 output tile, BK=16, 256 threads, 4x4 micro-tile per thread.
// A[m][k] = (1+eps)*X[m][k] + AGG[m][k] computed during staging.
#define BM 64
#define BN 64
#define BKK 16

__global__ __launch_bounds__(256) void gin_gemm_kernel(
    const float* __restrict__ X, const float* __restrict__ AGG,
    const float* __restrict__ W, const float* __restrict__ bias,
    const float* __restrict__ eps_arr, int layer, int do_relu,
    float* __restrict__ out, int M, int K, int N)
{
    __shared__ float As[BKK][BM];   // transposed: As[k][m]
    __shared__ float Bs[BKK][BN];   // Bs[k][n]

    const int t  = threadIdx.x;
    const int bm = blockIdx.y * BM;
    const int bn = blockIdx.x * BN;
    const float epsv = 1.0f + eps_arr[layer];

    const int tx = t & 15;          // 0..15 -> column group
    const int ty = t >> 4;          // 0..15 -> row group

    // A staging: one float4 along K per thread
    const int la_m  = t >> 2;        // 0..63
    const int la_k4 = (t & 3) * 4;   // 0,4,8,12
    // B staging: one float4 along N per thread
    const int lb_k  = t >> 4;        // 0..15
    const int lb_n4 = (t & 15) * 4;  // 0..60

    float acc[4][4] = {};

    for (int k0 = 0; k0 < K; k0 += BKK) {
        // ---- stage A (fused h computation) ----
        float4 av = make_float4(0.f, 0.f, 0.f, 0.f);
        int gm = bm + la_m;
        if (gm < M) {
            const float4 xv = *reinterpret_cast<const float4*>(X   + (size_t)gm * K + k0 + la_k4);
            const float4 gv = *reinterpret_cast<const float4*>(AGG + (size_t)gm * K + k0 + la_k4);
            av.x = epsv * xv.x + gv.x;
            av.y = epsv * xv.y + gv.y;
            av.z = epsv * xv.z + gv.z;
            av.w = epsv * xv.w + gv.w;
        }
        As[la_k4 + 0][la_m] = av.x;
        As[la_k4 + 1][la_m] = av.y;
        As[la_k4 + 2][la_m] = av.z;
        As[la_k4 + 3][la_m] = av.w;

        // ---- stage B ----
        const float4 bv = *reinterpret_cast<const float4*>(W + (size_t)(k0 + lb_k) * N + bn + lb_n4);
        *reinterpret_cast<float4*>(&Bs[lb_k][lb_n4]) = bv;

        __syncthreads();

        #pragma unroll
        for (int k = 0; k < BKK; ++k) {
            float a[4], b[4];
            #pragma unroll
            for (int i = 0; i < 4; ++i) a[i] = As[k][ty * 4 + i];
            #pragma unroll
            for (int j = 0; j < 4; ++j) b[j] = Bs[k][tx * 4 + j];
            #pragma unroll
            for (int i = 0; i < 4; ++i)
                #pragma unroll
                for (int j = 0; j < 4; ++j)
                    acc[i][j] += a[i] * b[j];
        }

        __syncthreads();
    }

    // ---- epilogue: bias (+ReLU), vectorized store ----
    const int col = bn + tx * 4;
    const float4 bb = *reinterpret_cast<const float4*>(bias + col);
    #pragma unroll
    for (int i = 0; i < 4; ++i) {
        int row = bm + ty * 4 + i;
        if (row < M) {
            float4 o;
            o.x = acc[i][0] + bb.x;
            o.y = acc[i][1] + bb.y;
            o.z = acc[i][2] + bb.z;
            o.w = acc[i][3] + bb.w;
            if (do_relu) {
                o.x = fmaxf(o.x, 0.f);
                o.y = fmaxf(o.y, 0.f);
                o.z = fmaxf(o.z, 0.f);
                o.w = fmaxf(o.w, 0.f);
            }
            *reinterpret_cast<float4*>(out + (size_t)row * N + col) = o;
        }
    }
}

extern "C" void kernel_launch(void* const* d_in, const int* in_sizes, int n_in,
                              void* d_out, int out_size, void* d_ws, size_t ws_size,
                              hipStream_t stream)
{
    const float* x    = (const float*)d_in[0];
    const int*   ei   = (const int*)  d_in[1];
    const float* W1   = (const float*)d_in[2];
    const float* b1   = (const float*)d_in[3];
    const float* W2   = (const float*)d_in[4];
    const float* b2   = (const float*)d_in[5];
    const float* W3   = (const float*)d_in[6];
    const float* b3   = (const float*)d_in[7];
    const float* eps  = (const float*)d_in[8];

    const int M  = in_sizes[0] / 128;   // 50000 nodes
    const int nE = in_sizes[1] / 2;     // 800000 edges
    const int* srcI = ei;
    const int* dstI = ei + nE;

    float* agg = (float*)d_ws;
    float* h1  = agg + (size_t)M * 256;
    float* h2  = h1  + (size_t)M * 256;

    dim3 gemmGrid(256 / BN, (M + BM - 1) / BM);

    // ---------------- layer 1 (K = 128) ----------------
    hipMemsetAsync(agg, 0, (size_t)M * 128 * sizeof(float), stream);
    {
        long long tot = (long long)nE * (128 / 4);
        scatter_add_kernel<<<(int)((tot + 255) / 256), 256, 0, stream>>>(
            x, srcI, dstI, agg, 5, 31, tot);
    }
    gin_gemm_kernel<<<gemmGrid, 256, 0, stream>>>(
        x, agg, W1, b1, eps, 0, 1, h1, M, 128, 256);

    // ---------------- layer 2 (K = 256) ----------------
    hipMemsetAsync(agg, 0, (size_t)M * 256 * sizeof(float), stream);
    {
        long long tot = (long long)nE * (256 / 4);
        scatter_add_kernel<<<(int)((tot + 255) / 256), 256, 0, stream>>>(
            h1, srcI, dstI, agg, 6, 63, tot);
    }
    gin_gemm_kernel<<<gemmGrid, 256, 0, stream>>>(
        h1, agg, W2, b2, eps, 1, 1, h2, M, 256, 256);

    // ---------------- layer 3 (K = 256, no relu) -------
    hipMemsetAsync(agg, 0, (size_t)M * 256 * sizeof(float), stream);
    {
        long long tot = (long long)nE * (256 / 4);
        scatter_add_kernel<<<(int)((tot + 255) / 256), 256, 0, stream>>>(
            h2, srcI, dstI, agg, 6, 63, tot);
    }
    gin_gemm_kernel<<<gemmGrid, 256, 0, stream>>>(
        h2, agg, W3, b3, eps, 2, 0, (float*)d_out, M, 256, 256);
}

// Round 2
// 725.426 us; speedup vs baseline: 9.5684x; 9.5684x over previous
//
#include <hip/hip_runtime.h>

// ---------------------------------------------------------------------------
// GIN 3-layer forward, CSR aggregation (no fp32 atomics):
//   CSR build:  hist(dst) -> exclusive scan -> bucket scatter of src ids
//   per layer:  H[i] = (1+eps)*X[i] + sum_{j in adj(i)} X[j]   (gather, reg acc)
//               out  = H @ W + b  (+ReLU on layers 0,1)
// ---------------------------------------------------------------------------

__global__ __launch_bounds__(256) void hist_kernel(
    const int* __restrict__ dst, int* __restrict__ cnt, int nE)
{
    int e = blockIdx.x * 256 + threadIdx.x;
    if (e < nE) atomicAdd(&cnt[dst[e]], 1);
}

__global__ __launch_bounds__(1024) void exclusive_scan_kernel(
    const int* __restrict__ cnt, int* __restrict__ row_start, int n)
{
    __shared__ int sh[1024];
    __shared__ int carry;
    const int tid = threadIdx.x;
    if (tid == 0) carry = 0;
    __syncthreads();
    for (int base = 0; base < n; base += 1024) {
        int i = base + tid;
        int v = (i < n) ? cnt[i] : 0;
        sh[tid] = v;
        __syncthreads();
        #pragma unroll
        for (int off = 1; off < 1024; off <<= 1) {
            int t = (tid >= off) ? sh[tid - off] : 0;
            __syncthreads();
            sh[tid] += t;
            __syncthreads();
        }
        int incl = sh[tid];
        if (i < n) row_start[i] = carry + (incl - v);
        __syncthreads();
        if (tid == 1023) carry += sh[1023];
        __syncthreads();
    }
    if (tid == 0) row_start[n] = carry;
}

__global__ __launch_bounds__(256) void build_adj_kernel(
    const int* __restrict__ src, const int* __restrict__ dst,
    int* __restrict__ cursor, int* __restrict__ adj, int nE)
{
    int e = blockIdx.x * 256 + threadIdx.x;
    if (e < nE) {
        int p = atomicAdd(&cursor[dst[e]], 1);
        adj[p] = src[e];
    }
}

// One node per C/4 lanes; float4 per lane; register accumulation.
// Writes H = (1+eps)*X + agg.
template <int C>
__global__ __launch_bounds__(256) void aggregate_kernel(
    const float* __restrict__ X, const int* __restrict__ row_start,
    const int* __restrict__ adj, const float* __restrict__ eps_arr, int layer,
    float* __restrict__ H, int M)
{
    constexpr int TPN = C / 4;       // threads per node
    constexpr int NPB = 256 / TPN;   // nodes per block
    const int node = blockIdx.x * NPB + threadIdx.x / TPN;
    const int c4   = threadIdx.x % TPN;
    if (node >= M) return;

    const float epsv = 1.0f + eps_arr[layer];
    const float4* __restrict__ X4 = reinterpret_cast<const float4*>(X);

    const int s0 = row_start[node];
    const int s1 = row_start[node + 1];

    float4 acc = make_float4(0.f, 0.f, 0.f, 0.f);
    int j = s0;
    for (; j + 3 < s1; j += 4) {
        int a0 = adj[j], a1 = adj[j + 1], a2 = adj[j + 2], a3 = adj[j + 3];
        float4 v0 = X4[(size_t)a0 * TPN + c4];
        float4 v1 = X4[(size_t)a1 * TPN + c4];
        float4 v2 = X4[(size_t)a2 * TPN + c4];
        float4 v3 = X4[(size_t)a3 * TPN + c4];
        acc.x += v0.x + v1.x + v2.x + v3.x;
        acc.y += v0.y + v1.y + v2.y + v3.y;
        acc.z += v0.z + v1.z + v2.z + v3.z;
        acc.w += v0.w + v1.w + v2.w + v3.w;
    }
    for (; j < s1; ++j) {
        float4 v = X4[(size_t)adj[j] * TPN + c4];
        acc.x += v.x; acc.y += v.y; acc.z += v.z; acc.w += v.w;
    }

    const float4 xv = X4[(size_t)node * TPN + c4];
    float4 o;
    o.x = epsv * xv.x + acc.x;
    o.y = epsv * xv.y + acc.y;
    o.z = epsv * xv.z + acc.z;
    o.w = epsv * xv.w + acc.w;
    reinterpret_cast<float4*>(H)[(size_t)node * TPN + c4] = o;
}

// 64x64 output tile, BK=16, 256 threads, 4x4 micro-tile per thread.
#define BM 64
#define BN 64
#define BKK 16

__global__ __launch_bounds__(256) void gin_gemm_kernel(
    const float* __restrict__ A, const float* __restrict__ W,
    const float* __restrict__ bias, int do_relu,
    float* __restrict__ out, int M, int K, int N)
{
    __shared__ float As[BKK][BM];   // As[k][m]
    __shared__ float Bs[BKK][BN];   // Bs[k][n]

    const int t  = threadIdx.x;
    const int bm = blockIdx.y * BM;
    const int bn = blockIdx.x * BN;

    const int tx = t & 15;
    const int ty = t >> 4;

    const int la_m  = t >> 2;
    const int la_k4 = (t & 3) * 4;
    const int lb_k  = t >> 4;
    const int lb_n4 = (t & 15) * 4;

    float acc[4][4] = {};

    for (int k0 = 0; k0 < K; k0 += BKK) {
        float4 av = make_float4(0.f, 0.f, 0.f, 0.f);
        int gm = bm + la_m;
        if (gm < M)
            av = *reinterpret_cast<const float4*>(A + (size_t)gm * K + k0 + la_k4);
        As[la_k4 + 0][la_m] = av.x;
        As[la_k4 + 1][la_m] = av.y;
        As[la_k4 + 2][la_m] = av.z;
        As[la_k4 + 3][la_m] = av.w;

        const float4 bv = *reinterpret_cast<const float4*>(W + (size_t)(k0 + lb_k) * N + bn + lb_n4);
        *reinterpret_cast<float4*>(&Bs[lb_k][lb_n4]) = bv;

        __syncthreads();

        #pragma unroll
        for (int k = 0; k < BKK; ++k) {
            float a[4], b[4];
            #pragma unroll
            for (int i = 0; i < 4; ++i) a[i] = As[k][ty * 4 + i];
            #pragma unroll
            for (int j = 0; j < 4; ++j) b[j] = Bs[k][tx * 4 + j];
            #pragma unroll
            for (int i = 0; i < 4; ++i)
                #pragma unroll
                for (int j = 0; j < 4; ++j)
                    acc[i][j] += a[i] * b[j];
        }

        __syncthreads();
    }

    const int col = bn + tx * 4;
    const float4 bb = *reinterpret_cast<const float4*>(bias + col);
    #pragma unroll
    for (int i = 0; i < 4; ++i) {
        int row = bm + ty * 4 + i;
        if (row < M) {
            float4 o;
            o.x = acc[i][0] + bb.x;
            o.y = acc[i][1] + bb.y;
            o.z = acc[i][2] + bb.z;
            o.w = acc[i][3] + bb.w;
            if (do_relu) {
                o.x = fmaxf(o.x, 0.f);
                o.y = fmaxf(o.y, 0.f);
                o.z = fmaxf(o.z, 0.f);
                o.w = fmaxf(o.w, 0.f);
            }
            *reinterpret_cast<float4*>(out + (size_t)row * N + col) = o;
        }
    }
}

extern "C" void kernel_launch(void* const* d_in, const int* in_sizes, int n_in,
                              void* d_out, int out_size, void* d_ws, size_t ws_size,
                              hipStream_t stream)
{
    const float* x    = (const float*)d_in[0];
    const int*   ei   = (const int*)  d_in[1];
    const float* W1   = (const float*)d_in[2];
    const float* b1   = (const float*)d_in[3];
    const float* W2   = (const float*)d_in[4];
    const float* b2   = (const float*)d_in[5];
    const float* W3   = (const float*)d_in[6];
    const float* b3   = (const float*)d_in[7];
    const float* eps  = (const float*)d_in[8];

    const int M  = in_sizes[0] / 128;   // 50000
    const int nE = in_sizes[1] / 2;     // 800000
    const int* srcI = ei;
    const int* dstI = ei + nE;

    // workspace layout
    float* Abuf = (float*)d_ws;                       // M*256 f32
    float* hbuf = Abuf + (size_t)M * 256;             // M*256 f32
    int*   cnt       = (int*)(hbuf + (size_t)M * 256);// M
    int*   row_start = cnt + M;                       // M+1
    int*   cursor    = row_start + M + 2;             // M
    int*   adj       = cursor + M;                    // nE

    // ---- CSR build ----
    hipMemsetAsync(cnt, 0, (size_t)M * sizeof(int), stream);
    hist_kernel<<<(nE + 255) / 256, 256, 0, stream>>>(dstI, cnt, nE);
    exclusive_scan_kernel<<<1, 1024, 0, stream>>>(cnt, row_start, M);
    hipMemcpyAsync(cursor, row_start, (size_t)M * sizeof(int),
                   hipMemcpyDeviceToDevice, stream);
    build_adj_kernel<<<(nE + 255) / 256, 256, 0, stream>>>(srcI, dstI, cursor, adj, nE);

    dim3 gemmGrid(256 / BN, (M + BM - 1) / BM);

    // ---- layer 1 (K=128) ----
    {
        constexpr int NPB = 256 / (128 / 4);  // 8 nodes/block
        aggregate_kernel<128><<<(M + NPB - 1) / NPB, 256, 0, stream>>>(
            x, row_start, adj, eps, 0, Abuf, M);
    }
    gin_gemm_kernel<<<gemmGrid, 256, 0, stream>>>(Abuf, W1, b1, 1, hbuf, M, 128, 256);

    // ---- layer 2 (K=256) ----
    {
        constexpr int NPB = 256 / (256 / 4);  // 4 nodes/block
        aggregate_kernel<256><<<(M + NPB - 1) / NPB, 256, 0, stream>>>(
            hbuf, row_start, adj, eps, 1, Abuf, M);
    }
    gin_gemm_kernel<<<gemmGrid, 256, 0, stream>>>(Abuf, W2, b2, 1, hbuf, M, 256, 256);

    // ---- layer 3 (K=256, no relu) ----
    {
        constexpr int NPB = 256 / (256 / 4);
        aggregate_kernel<256><<<(M + NPB - 1) / NPB, 256, 0, stream>>>(
            hbuf, row_start, adj, eps, 2, Abuf, M);
    }
    gin_gemm_kernel<<<gemmGrid, 256, 0, stream>>>(Abuf, W3, b3, 0, (float*)d_out, M, 256, 256);
}

// Round 3
// 341.568 us; speedup vs baseline: 20.3216x; 2.1238x over previous
//
#include <hip/hip_runtime.h>

// ---------------------------------------------------------------------------
// GIN 3-layer forward, bf16 pipeline:
//   CSR build (hist -> hierarchical scan -> bucket scatter)
//   per layer: H = (1+eps)*X + gather-sum  (bf16 in, fp32 acc, bf16 out)
//              out = H @ W + b (MFMA bf16 16x16x32, fp32 acc), +ReLU layers 0,1
//   final layer writes fp32 to d_out.
// ---------------------------------------------------------------------------

typedef __attribute__((ext_vector_type(8))) short short8;
typedef __attribute__((ext_vector_type(4))) float f32x4;

__device__ inline unsigned short f2bf(float f) {
    union { float f; unsigned u; } v; v.f = f;
    unsigned r = v.u + 0x7fffu + ((v.u >> 16) & 1u);   // RNE
    return (unsigned short)(r >> 16);
}
__device__ inline float bflo(unsigned u) { return __uint_as_float(u << 16); }
__device__ inline float bfhi(unsigned u) { return __uint_as_float(u & 0xffff0000u); }

// ---------------- CSR build ----------------

__global__ __launch_bounds__(256) void hist_kernel(
    const int* __restrict__ dst, int* __restrict__ cnt, int nE)
{
    int e = blockIdx.x * 256 + threadIdx.x;
    if (e < nE) atomicAdd(&cnt[dst[e]], 1);
}

__global__ __launch_bounds__(1024) void scan1_kernel(
    const int* __restrict__ cnt, int* __restrict__ excl,
    int* __restrict__ bsum, int n)
{
    __shared__ int sh[1024];
    const int tid = threadIdx.x;
    const int i = blockIdx.x * 1024 + tid;
    int v = (i < n) ? cnt[i] : 0;
    sh[tid] = v;
    __syncthreads();
    #pragma unroll
    for (int off = 1; off < 1024; off <<= 1) {
        int t = (tid >= off) ? sh[tid - off] : 0;
        __syncthreads();
        sh[tid] += t;
        __syncthreads();
    }
    if (i < n) excl[i] = sh[tid] - v;
    if (tid == 1023) bsum[blockIdx.x] = sh[1023];
}

__global__ __launch_bounds__(64) void scan2_kernel(
    const int* __restrict__ bsum, int* __restrict__ boffs, int nb)
{
    __shared__ int sh[64];
    const int tid = threadIdx.x;
    int v = (tid < nb) ? bsum[tid] : 0;
    sh[tid] = v;
    __syncthreads();
    #pragma unroll
    for (int off = 1; off < 64; off <<= 1) {
        int t = (tid >= off) ? sh[tid - off] : 0;
        __syncthreads();
        sh[tid] += t;
        __syncthreads();
    }
    boffs[tid] = sh[tid] - v;  // exclusive
}

__global__ __launch_bounds__(1024) void scan3_kernel(
    const int* __restrict__ excl, const int* __restrict__ boffs,
    int* __restrict__ row_start, int* __restrict__ cursor, int n, int nE)
{
    const int i = blockIdx.x * 1024 + threadIdx.x;
    if (i < n) {
        int v = excl[i] + boffs[blockIdx.x];
        row_start[i] = v;
        cursor[i] = v;
    }
    if (i == 0) row_start[n] = nE;
}

__global__ __launch_bounds__(256) void build_adj_kernel(
    const int* __restrict__ src, const int* __restrict__ dst,
    int* __restrict__ cursor, int* __restrict__ adj, int nE)
{
    int e = blockIdx.x * 256 + threadIdx.x;
    if (e < nE) {
        int p = atomicAdd(&cursor[dst[e]], 1);
        adj[p] = src[e];
    }
}

// ---------------- dtype conversion ----------------

__global__ __launch_bounds__(256) void convert_x_kernel(
    const float* __restrict__ in, unsigned short* __restrict__ out, int n4)
{
    int i = blockIdx.x * 256 + threadIdx.x;
    if (i >= n4) return;
    float4 v = reinterpret_cast<const float4*>(in)[i];
    ushort4 o;
    o.x = f2bf(v.x); o.y = f2bf(v.y); o.z = f2bf(v.z); o.w = f2bf(v.w);
    reinterpret_cast<ushort4*>(out)[i] = o;
}

// Wt[n*K+k] = bf16(W[k*N+n])
__global__ __launch_bounds__(256) void convert_wt_kernel(
    const float* __restrict__ W, unsigned short* __restrict__ Wt,
    int kshift, int N, int total)
{
    int idx = blockIdx.x * 256 + threadIdx.x;
    if (idx >= total) return;
    int n = idx >> kshift;
    int k = idx & ((1 << kshift) - 1);
    Wt[idx] = f2bf(W[(size_t)k * N + n]);
}

// ---------------- aggregation (bf16 gather, fp32 acc) ----------------

#define ACC8(v) { acc[0]+=bflo(v.x); acc[1]+=bfhi(v.x); acc[2]+=bflo(v.y); acc[3]+=bfhi(v.y); \
                  acc[4]+=bflo(v.z); acc[5]+=bfhi(v.z); acc[6]+=bflo(v.w); acc[7]+=bfhi(v.w); }

template <int C>
__global__ __launch_bounds__(256) void aggregate_bf16(
    const unsigned short* __restrict__ X, const int* __restrict__ row_start,
    const int* __restrict__ adj, const float* __restrict__ eps_arr, int layer,
    unsigned short* __restrict__ H, int M)
{
    constexpr int TPN = C / 8;        // lanes per node (16B = 8 bf16 each)
    constexpr int NPB = 256 / TPN;
    const int node = blockIdx.x * NPB + (threadIdx.x / TPN);
    const int c8   = threadIdx.x & (TPN - 1);
    if (node >= M) return;

    const uint4* __restrict__ X4 = reinterpret_cast<const uint4*>(X);

    float acc[8] = {0.f,0.f,0.f,0.f,0.f,0.f,0.f,0.f};
    const int s0 = row_start[node];
    const int s1 = row_start[node + 1];

    int j = s0;
    for (; j + 3 < s1; j += 4) {
        int a0 = adj[j], a1 = adj[j+1], a2 = adj[j+2], a3 = adj[j+3];
        uint4 v0 = X4[(size_t)a0 * TPN + c8];
        uint4 v1 = X4[(size_t)a1 * TPN + c8];
        uint4 v2 = X4[(size_t)a2 * TPN + c8];
        uint4 v3 = X4[(size_t)a3 * TPN + c8];
        ACC8(v0); ACC8(v1); ACC8(v2); ACC8(v3);
    }
    for (; j < s1; ++j) {
        uint4 v = X4[(size_t)adj[j] * TPN + c8];
        ACC8(v);
    }

    const uint4 xv = X4[(size_t)node * TPN + c8];
    const float epsv = 1.0f + eps_arr[layer];
    float o[8];
    o[0] = epsv * bflo(xv.x) + acc[0]; o[1] = epsv * bfhi(xv.x) + acc[1];
    o[2] = epsv * bflo(xv.y) + acc[2]; o[3] = epsv * bfhi(xv.y) + acc[3];
    o[4] = epsv * bflo(xv.z) + acc[4]; o[5] = epsv * bfhi(xv.z) + acc[5];
    o[6] = epsv * bflo(xv.w) + acc[6]; o[7] = epsv * bfhi(xv.w) + acc[7];

    uint4 ov;
    ov.x = (unsigned)f2bf(o[0]) | ((unsigned)f2bf(o[1]) << 16);
    ov.y = (unsigned)f2bf(o[2]) | ((unsigned)f2bf(o[3]) << 16);
    ov.z = (unsigned)f2bf(o[4]) | ((unsigned)f2bf(o[5]) << 16);
    ov.w = (unsigned)f2bf(o[6]) | ((unsigned)f2bf(o[7]) << 16);
    reinterpret_cast<uint4*>(H)[(size_t)node * TPN + c8] = ov;
}

// ---------------- MFMA GEMM: out[M,N] = A[M,K] @ Wt[N,K]^T + b ----------------
// 128x64 tile, 256 threads = 4 waves (2x2), each wave 64x32 (4x2 16x16 frags).

#define GBM 128
#define GBN 64
#define GBK 32

template <int RELU, int BF16OUT>
__global__ __launch_bounds__(256) void gemm_mfma(
    const unsigned short* __restrict__ A, const unsigned short* __restrict__ Wt,
    const float* __restrict__ bias, void* __restrict__ out, int M, int K, int N)
{
    __shared__ __align__(16) short As[GBM][GBK + 8];
    __shared__ __align__(16) short Bs[GBN][GBK + 8];

    const int t    = threadIdx.x;
    const int bm   = blockIdx.y * GBM;
    const int bn   = blockIdx.x * GBN;
    const int w    = t >> 6, lane = t & 63;
    const int wr   = w >> 1, wc = w & 1;
    const int lr   = lane & 15, ko = lane >> 4;

    const int am = t >> 1;          // A staging row 0..127
    const int ah = (t & 1) * 16;    // 16 shorts (32B) halves
    const int bnr = t >> 2;         // B staging row 0..63
    const int bq  = (t & 3) * 8;    // 8 shorts (16B) quarters

    f32x4 acc[4][2] = {};

    for (int k0 = 0; k0 < K; k0 += GBK) {
        // stage A tile
        uint4 av0 = {0,0,0,0}, av1 = {0,0,0,0};
        int gm = bm + am;
        if (gm < M) {
            const uint4* p = reinterpret_cast<const uint4*>(A + (size_t)gm * K + k0 + ah);
            av0 = p[0]; av1 = p[1];
        }
        *reinterpret_cast<uint4*>(&As[am][ah])     = av0;
        *reinterpret_cast<uint4*>(&As[am][ah + 8]) = av1;
        // stage B tile (Wt is [N][K] row-major)
        const uint4 bv = *reinterpret_cast<const uint4*>(Wt + (size_t)(bn + bnr) * K + k0 + bq);
        *reinterpret_cast<uint4*>(&Bs[bnr][bq]) = bv;

        __syncthreads();

        short8 af[4], bfr[2];
        #pragma unroll
        for (int fm = 0; fm < 4; ++fm)
            af[fm] = *reinterpret_cast<const short8*>(&As[wr*64 + fm*16 + lr][ko*8]);
        #pragma unroll
        for (int fn = 0; fn < 2; ++fn)
            bfr[fn] = *reinterpret_cast<const short8*>(&Bs[wc*32 + fn*16 + lr][ko*8]);
        #pragma unroll
        for (int fm = 0; fm < 4; ++fm)
            #pragma unroll
            for (int fn = 0; fn < 2; ++fn)
                acc[fm][fn] = __builtin_amdgcn_mfma_f32_16x16x32_bf16(
                    af[fm], bfr[fn], acc[fm][fn], 0, 0, 0);

        __syncthreads();
    }

    // epilogue: C/D layout col = lane&15, row = (lane>>4)*4 + r
    #pragma unroll
    for (int fn = 0; fn < 2; ++fn) {
        const int col = bn + wc*32 + fn*16 + lr;
        const float bb = bias[col];
        #pragma unroll
        for (int fm = 0; fm < 4; ++fm) {
            const int rbase = bm + wr*64 + fm*16 + ko*4;
            #pragma unroll
            for (int r = 0; r < 4; ++r) {
                const int row = rbase + r;
                if (row < M) {
                    float v = acc[fm][fn][r] + bb;
                    if (RELU) v = fmaxf(v, 0.f);
                    if (BF16OUT)
                        ((unsigned short*)out)[(size_t)row * N + col] = f2bf(v);
                    else
                        ((float*)out)[(size_t)row * N + col] = v;
                }
            }
        }
    }
}

// ---------------- launch ----------------

extern "C" void kernel_launch(void* const* d_in, const int* in_sizes, int n_in,
                              void* d_out, int out_size, void* d_ws, size_t ws_size,
                              hipStream_t stream)
{
    const float* x   = (const float*)d_in[0];
    const int*   ei  = (const int*)  d_in[1];
    const float* W1  = (const float*)d_in[2];
    const float* b1  = (const float*)d_in[3];
    const float* W2  = (const float*)d_in[4];
    const float* b2  = (const float*)d_in[5];
    const float* W3  = (const float*)d_in[6];
    const float* b3  = (const float*)d_in[7];
    const float* eps = (const float*)d_in[8];

    const int M  = in_sizes[0] / 128;   // 50000
    const int nE = in_sizes[1] / 2;     // 800000
    const int* srcI = ei;
    const int* dstI = ei + nE;

    // workspace layout
    char* p = (char*)d_ws;
    unsigned short* xb   = (unsigned short*)p; p += (size_t)M * 128 * 2;
    unsigned short* A1   = (unsigned short*)p; p += (size_t)M * 128 * 2;
    unsigned short* bufA = (unsigned short*)p; p += (size_t)M * 256 * 2;
    unsigned short* bufB = (unsigned short*)p; p += (size_t)M * 256 * 2;
    unsigned short* Wt1  = (unsigned short*)p; p += (size_t)128 * 256 * 2;
    unsigned short* Wt2  = (unsigned short*)p; p += (size_t)256 * 256 * 2;
    unsigned short* Wt3  = (unsigned short*)p; p += (size_t)256 * 256 * 2;
    int* cnt       = (int*)p; p += (size_t)M * 4;
    int* excl      = (int*)p; p += (size_t)M * 4;
    int* bsum      = (int*)p; p += 64 * 4;
    int* boffs     = (int*)p; p += 64 * 4;
    int* row_start = (int*)p; p += (size_t)(M + 2) * 4;
    int* cursor    = (int*)p; p += (size_t)M * 4;
    int* adj       = (int*)p; p += (size_t)nE * 4;

    const int nbl = (M + 1023) / 1024;   // 49

    // CSR build
    hipMemsetAsync(cnt, 0, (size_t)M * sizeof(int), stream);
    hist_kernel<<<(nE + 255) / 256, 256, 0, stream>>>(dstI, cnt, nE);
    scan1_kernel<<<nbl, 1024, 0, stream>>>(cnt, excl, bsum, M);
    scan2_kernel<<<1, 64, 0, stream>>>(bsum, boffs, nbl);
    scan3_kernel<<<nbl, 1024, 0, stream>>>(excl, boffs, row_start, cursor, M, nE);
    build_adj_kernel<<<(nE + 255) / 256, 256, 0, stream>>>(srcI, dstI, cursor, adj, nE);

    // conversions
    convert_x_kernel<<<(M * 128 / 4 + 255) / 256, 256, 0, stream>>>(x, xb, M * 128 / 4);
    convert_wt_kernel<<<(128 * 256 + 255) / 256, 256, 0, stream>>>(W1, Wt1, 7, 256, 128 * 256);
    convert_wt_kernel<<<(256 * 256 + 255) / 256, 256, 0, stream>>>(W2, Wt2, 8, 256, 256 * 256);
    convert_wt_kernel<<<(256 * 256 + 255) / 256, 256, 0, stream>>>(W3, Wt3, 8, 256, 256 * 256);

    const dim3 ggrid(256 / GBN, (M + GBM - 1) / GBM);

    // layer 1 (K=128)
    aggregate_bf16<128><<<(M + 15) / 16, 256, 0, stream>>>(xb, row_start, adj, eps, 0, A1, M);
    gemm_mfma<1, 1><<<ggrid, 256, 0, stream>>>(A1, Wt1, b1, bufA, M, 128, 256);

    // layer 2 (K=256)
    aggregate_bf16<256><<<(M + 7) / 8, 256, 0, stream>>>(bufA, row_start, adj, eps, 1, bufB, M);
    gemm_mfma<1, 1><<<ggrid, 256, 0, stream>>>(bufB, Wt2, b2, bufA, M, 256, 256);

    // layer 3 (K=256, no relu, fp32 out)
    aggregate_bf16<256><<<(M + 7) / 8, 256, 0, stream>>>(bufA, row_start, adj, eps, 2, bufB, M);
    gemm_mfma<0, 0><<<ggrid, 256, 0, stream>>>(bufB, Wt3, b3, d_out, M, 256, 256);
}